// Round 4
// baseline (62.836 us; speedup 1.0000x reference)
//
#include <hip/hip_runtime.h>
#include <math.h>

#define NS 96
#define NSEG 95
#define LPR 8      // lanes per ray (phase A)
#define SPL 12     // segments per lane
#define RPB 32     // rays per block
#define USTR 97    // LDS u row stride (odd -> 2-way-free banks)

__device__ __forceinline__ float fexp2(float x) { return __builtin_amdgcn_exp2f(x); }
__device__ __forceinline__ float flog2(float x) { return __builtin_amdgcn_logf(x); }

// ---------------------------------------------------------------------------
__global__ void init_mm_kernel(unsigned* mm) {
    mm[0] = 0x7F7FFFFFu;  // FLT_MAX bits  -> min accumulator
    mm[1] = 0u;           // max accumulator (depths > 0)
}

// ---------------------------------------------------------------------------
__global__ __launch_bounds__(256) void minmax_kernel(
    const float4* __restrict__ dep4, unsigned* mm, int n4)
{
    int idx = blockIdx.x * blockDim.x + threadIdx.x;
    int stride = gridDim.x * blockDim.x;
    float lo = __int_as_float(0x7F7FFFFF);
    float hi = 0.0f;
    for (int i = idx; i < n4; i += stride) {
        float4 v = dep4[i];
        lo = fminf(lo, fminf(fminf(v.x, v.y), fminf(v.z, v.w)));
        hi = fmaxf(hi, fmaxf(fmaxf(v.x, v.y), fmaxf(v.z, v.w)));
    }
#pragma unroll
    for (int off = 32; off; off >>= 1) {
        lo = fminf(lo, __shfl_xor(lo, off));
        hi = fmaxf(hi, __shfl_xor(hi, off));
    }
    __shared__ float slo[4], shi[4];
    int wave = threadIdx.x >> 6;
    if ((threadIdx.x & 63) == 0) { slo[wave] = lo; shi[wave] = hi; }
    __syncthreads();
    if (threadIdx.x == 0) {
        lo = fminf(fminf(slo[0], slo[1]), fminf(slo[2], slo[3]));
        hi = fmaxf(fmaxf(shi[0], shi[1]), fmaxf(shi[2], shi[3]));
        atomicMin(&mm[0], __float_as_uint(lo));
        atomicMax(&mm[1], __float_as_uint(hi));
    }
}

// ---------------------------------------------------------------------------
// Phase A: 8 lanes/ray compute weights + per-sample color coefficients
//          u_s = (w_{s-1}+w_s)/2 into LDS; depth composite done here.
// Phase B: colors consumed fully coalesced (f4 f = tid+256q); each aligned
//          8-lane group lies in one ray (8 | 72); width-8 butterfly ->
//          3 LDS atomic adds per group.
// ---------------------------------------------------------------------------
__global__ __launch_bounds__(256) void raymarch_kernel(
    const float4* __restrict__ col4,
    const float* __restrict__ densities,
    const float* __restrict__ depths,
    const unsigned* __restrict__ mm,
    float* __restrict__ out_rgb,
    float* __restrict__ out_depth,
    float* __restrict__ out_w,
    int n_rays)
{
    __shared__ float su[RPB * USTR];   // u coefficients  (~12.4 KB)
    __shared__ float acc[RPB * 3];     // rgb accumulators

    const int tid  = threadIdx.x;
    const int base = blockIdx.x * RPB;

    if (tid < RPB * 3) acc[tid] = 0.0f;

    // ---- hoisted coalesced color loads (in flight under phase A) ----------
    const float4* gc = col4 + (size_t)base * 72;
    const int nf4 = (min(base + RPB, n_rays) - base) * 72;
    float4 cf[9];
#pragma unroll
    for (int q = 0; q < 9; ++q) {
        int f = tid + 256 * q;
        cf[q] = (f < nf4) ? gc[f] : make_float4(0.f, 0.f, 0.f, 0.f);
    }

    // ======================= Phase A ========================================
    const int lane = tid & 63;
    const int sub  = lane & 7;
    const int rloc = (tid >> 6) * 8 + (lane >> 3);
    const int ray  = base + rloc;
    const int rc   = min(ray, n_rays - 1);
    const bool safe = (ray < n_rays);

    const int s0 = sub * SPL;
    const float* dep = depths    + (size_t)rc * NS + s0;
    const float* den = densities + (size_t)rc * NS + s0;

    float d[13], nd[13];
#pragma unroll
    for (int q = 0; q < 3; ++q) {
        float4 v = *(const float4*)(dep + 4 * q);
        d[4*q+0] = v.x; d[4*q+1] = v.y; d[4*q+2] = v.z; d[4*q+3] = v.w;
        float4 u = *(const float4*)(den + 4 * q);
        nd[4*q+0] = u.x; nd[4*q+1] = u.y; nd[4*q+2] = u.z; nd[4*q+3] = u.w;
    }
    // 13th sample; clamp for sub==7 -> delta=0 -> e=1, alpha=0, w=0 (exact)
    {
        int i13 = (sub == 7) ? 11 : 12;
        d[12]  = dep[i13];
        nd[12] = den[i13];
    }

    // e_j = exp(-softplus(mid-1)*delta), stable form, native exp2/log2
    const float LOG2E = 1.4426950408889634f;
    float e[SPL];
#pragma unroll
    for (int j = 0; j < SPL; ++j) {
        float delta = d[j+1] - d[j];
        float x = (nd[j] + nd[j+1]) * 0.5f - 1.0f;
        float sp2 = fmaxf(x, 0.f) * LOG2E + flog2(1.0f + fexp2(-fabsf(x) * LOG2E));
        e[j] = fexp2(-delta * sp2);
    }

    // local product + width-8 inclusive scan -> exclusive transmittance
    float P = 1.0f;
#pragma unroll
    for (int j = 0; j < SPL; ++j) P *= (e[j] + 1e-10f);
    float inc = P;
#pragma unroll
    for (int off = 1; off < LPR; off <<= 1) {
        float t = __shfl_up(inc, off, LPR);
        if (sub >= off) inc *= t;
    }
    float Tex = __shfl_up(inc, 1, LPR);
    if (sub == 0) Tex = 1.0f;

    // weights
    float w[SPL];
    {
        float T = Tex;
#pragma unroll
        for (int j = 0; j < SPL; ++j) {
            w[j] = (1.0f - e[j]) * T;
            T *= (e[j] + 1e-10f);
        }
    }
    float wprev = __shfl_up(w[SPL-1], 1, LPR);
    if (sub == 0) wprev = 0.0f;

    // u into LDS + weight/depth outputs
    float* ur = su + rloc * USTR + s0;
    float* wg = out_w + (size_t)rc * NSEG + s0;
    float sw = 0.f, sd = 0.f;
#pragma unroll
    for (int j = 0; j < SPL; ++j) {
        ur[j] = 0.5f * (wprev + w[j]);
        wprev = w[j];
        sw += w[j];
        sd += w[j] * ((d[j] + d[j+1]) * 0.5f);
        if (safe && (sub < 7 || j < 11)) wg[j] = w[j];
    }

#pragma unroll
    for (int off = 1; off < LPR; off <<= 1) {
        sw += __shfl_xor(sw, off, LPR);
        sd += __shfl_xor(sd, off, LPR);
    }
    if (sub == 0 && safe) {
        float cd = sd / sw;
        if (isnan(cd)) cd = __int_as_float(0x7F800000);
        cd = fminf(fmaxf(cd, __uint_as_float(mm[0])), __uint_as_float(mm[1]));
        out_depth[ray] = cd;
    }

    __syncthreads();

    // ======================= Phase B ========================================
#pragma unroll
    for (int q = 0; q < 9; ++q) {
        int f = tid + 256 * q;       // f4 index in block tile (ray = f/72)
        int r  = f / 72;
        int p  = 4 * f - 288 * r;    // float offset within ray [0..284]
        int sB = p / 3;
        int r0 = p - 3 * sB;         // 0..2
        const float* urow = su + r * USTR;
        float uA = urow[sB], uB = urow[sB + 1];

        float v0 = cf[q].x, v1 = cf[q].y, v2 = cf[q].z, v3 = cf[q].w;
        float pr = 0.f, pg = 0.f, pb = 0.f;
#pragma unroll
        for (int k = 0; k < 4; ++k) {
            float vk = (k == 0) ? v0 : (k == 1) ? v1 : (k == 2) ? v2 : v3;
            int t = r0 + k;          // 0..5
            bool hi = (t >= 3);
            float uu = hi ? uB : uA;
            int ch = hi ? t - 3 : t;
            float cv = vk * uu;
            pr += (ch == 0) ? cv : 0.f;
            pg += (ch == 1) ? cv : 0.f;
            pb += (ch == 2) ? cv : 0.f;
        }
        // width-8 butterfly (each aligned 8-lane group is one ray)
#pragma unroll
        for (int off = 1; off < 8; off <<= 1) {
            pr += __shfl_xor(pr, off, 8);
            pg += __shfl_xor(pg, off, 8);
            pb += __shfl_xor(pb, off, 8);
        }
        if ((tid & 7) == 0 && f < nf4) {
            atomicAdd(&acc[r * 3 + 0], pr);
            atomicAdd(&acc[r * 3 + 1], pg);
            atomicAdd(&acc[r * 3 + 2], pb);
        }
    }

    __syncthreads();

    if (tid < RPB * 3) {
        int r = tid / 3;
        if (base + r < n_rays)
            out_rgb[(size_t)base * 3 + tid] = acc[tid] * 2.0f - 1.0f;
    }
}

// ---------------------------------------------------------------------------
extern "C" void kernel_launch(void* const* d_in, const int* in_sizes, int n_in,
                              void* d_out, int out_size, void* d_ws, size_t ws_size,
                              hipStream_t stream) {
    const float* colors    = (const float*)d_in[0];
    const float* densities = (const float*)d_in[1];
    const float* depths    = (const float*)d_in[2];

    const int n_rays = in_sizes[1] / NS;

    float* out       = (float*)d_out;
    float* out_rgb   = out;
    float* out_depth = out + (size_t)n_rays * 3;
    float* out_w     = out + (size_t)n_rays * 4;

    unsigned* mm = (unsigned*)d_ws;

    hipLaunchKernelGGL(init_mm_kernel, dim3(1), dim3(1), 0, stream, mm);

    const int n4 = n_rays * NS / 4;
    hipLaunchKernelGGL(minmax_kernel, dim3(512), dim3(256), 0, stream,
                       (const float4*)depths, mm, n4);

    hipLaunchKernelGGL(raymarch_kernel,
                       dim3((n_rays + RPB - 1) / RPB), dim3(256), 0, stream,
                       (const float4*)colors, densities, depths, mm,
                       out_rgb, out_depth, out_w, n_rays);
}